// Round 7
// baseline (62.453 us; speedup 1.0000x reference)
//
#include <hip/hip_runtime.h>
#include <hip/hip_bf16.h>
#include <stdint.h>

typedef __attribute__((ext_vector_type(8))) short bf16x8;
typedef __attribute__((ext_vector_type(4))) float f32x4;
typedef __attribute__((ext_vector_type(16))) float f32x16;

#define MFMA32(a, b, c) __builtin_amdgcn_mfma_f32_32x32x16_bf16((a), (b), (c), 0, 0, 0)

__device__ __forceinline__ unsigned short f2bf_rn(float f) {
    union { __bf16 b; unsigned short u; } v;
    v.b = (__bf16)f;
    return v.u;
}

// pack 2 floats -> 2 bf16 in a uint (compiler fuses to v_cvt_pk_bf16_f32)
__device__ __forceinline__ unsigned int pk2(float lo, float hi) {
    union { unsigned short s[2]; unsigned int u; } r;
    r.s[0] = f2bf_rn(lo); r.s[1] = f2bf_rn(hi);
    return r.u;
}

__device__ __forceinline__ void gload_lds16(const void* g, void* l) {
    __builtin_amdgcn_global_load_lds(
        (const __attribute__((address_space(1))) void*)g,
        (__attribute__((address_space(3))) void*)l, 16, 0, 0);
}

// ---------------------------------------------------------------------------
// prep_h: transpose each 128x128 fp32 block of the 8 H tensors to bf16.
//   ht[j][blk][k][r] = h_j[blk][r][k]   (j = input order hr1,hi1,...,hi4)
// Lt_c = ht[c], Wt_c = ht[rperm[c]].
// ---------------------------------------------------------------------------
__global__ __launch_bounds__(256) void prep_h(
    const float* __restrict__ h0, const float* __restrict__ h1,
    const float* __restrict__ h2, const float* __restrict__ h3,
    const float* __restrict__ h4, const float* __restrict__ h5,
    const float* __restrict__ h6, const float* __restrict__ h7,
    unsigned short* __restrict__ ht)
{
    const float* hmap[8] = {h0, h1, h2, h3, h4, h5, h6, h7};
    const int wg = blockIdx.x;        // 64 = j(8) x blk(8)
    const float* src = hmap[wg >> 3] + (wg & 7) * 16384;
    unsigned short* dst = ht + wg * 16384;
    __shared__ unsigned short tile[128 * 129];
    const int t = threadIdx.x;
    #pragma unroll 4
    for (int i = 0; i < 64; ++i) {
        int idx = t + 256 * i, r = idx >> 7, k = idx & 127;
        tile[r * 129 + k] = f2bf_rn(src[idx]);
    }
    __syncthreads();
    #pragma unroll 4
    for (int i = 0; i < 64; ++i) {
        int idx = t + 256 * i, k = idx >> 7, r = idx & 127;
        dst[idx] = tile[r * 129 + k];
    }
}

// ---------------------------------------------------------------------------
// prep_x: x (B,16,64,16,64,2) fp32 -> permuted bf16 planes Xre/Xim (B,1024,1024)
// ---------------------------------------------------------------------------
__global__ __launch_bounds__(256) void prep_x(
    const float* __restrict__ x, const int* __restrict__ perm,
    unsigned short* __restrict__ xre, unsigned short* __restrict__ xim)
{
    const int id = blockIdx.x * 256 + threadIdx.x;   // 4*1024*256 total
    const int b = id >> 18;
    const int row = (id >> 8) & 1023;
    const int col0 = (id & 255) * 4;
    const int n1 = perm[row >> 6], r1 = row & 63;
    const int n2 = perm[col0 >> 6], r2 = col0 & 63;
    const int src = (((b * 16 + n1) * 64 + r1) * 16 + n2) * 64 + r2;  // float2 units
    const float4* s = (const float4*)(x + src * 2);
    float4 v0 = s[0], v1 = s[1];
    ushort4 re, im;
    re.x = f2bf_rn(v0.x); re.y = f2bf_rn(v0.z); re.z = f2bf_rn(v1.x); re.w = f2bf_rn(v1.z);
    im.x = f2bf_rn(v0.y); im.y = f2bf_rn(v0.w); im.z = f2bf_rn(v1.y); im.w = f2bf_rn(v1.w);
    const int o = id * 4;
    *(ushort4*)(xre + o) = re;
    *(ushort4*)(xim + o) = im;
}

// ---------------------------------------------------------------------------
// bilin_main: 256 WGs = (b,p,q), q = bid&7 (XCD-locked). 512 threads = 8
// waves: wn = wid&3 (32-col group), h = wid>>2 (64-row half, split-K pair).
// 32x32x16 MFMA.  X fragments live in REGISTERS (loaded from the bf16 planes
// once per g, reused across 4 c-terms).  W and Lt both double-buffered in
// LDS via gload_lds -> ONE barrier per c-term; each stage is issued a full
// c-iteration (~2300 cyc) before the barrier that drains it.
// Per c: stage A  U[64x32] = X[h-rows] . W_c[:,wn-cols]   (wf from LDS)
//        in-reg transpose (cvt-pack + shfl_xor(32), verified R6)
//        stage B  Ypart[128x32] += Lt_c[., h-rows] . U    (lf from LDS)
// Epilogue sums the h=0/h=1 split-K partials through reused LDS.
// LDS swizzle: 16B chunk ch of row at LDS[row][ch] = G[row][ch ^ (row&15)].
// ---------------------------------------------------------------------------
__global__ __launch_bounds__(512, 2) void bilin_main(
    const unsigned short* __restrict__ xre,
    const unsigned short* __restrict__ xim,
    const unsigned short* __restrict__ ht,
    float* __restrict__ out)
{
    const int wg = blockIdx.x;
    const int q = wg & 7, p = (wg >> 3) & 7, b = wg >> 6;
    const int tid = threadIdx.x;
    const int lane = tid & 63, wid = tid >> 6;
    const int wn = wid & 3, h = wid >> 2;
    const int l31 = lane & 31, hl = lane >> 5;

    __shared__ __align__(16) unsigned short smem[65536];   // 128 KB
    // wlds[par] = smem + par*16384 ; llds[par] = smem + 32768 + par*16384

    constexpr int cseq[8]  = {0, 1, 6, 7, 2, 3, 4, 5};
    constexpr int rperm[8] = {0, 1, 3, 2, 4, 5, 7, 6};

    f32x16 yre[4], yim[4];
    #pragma unroll
    for (int i = 0; i < 4; ++i) {
        #pragma unroll
        for (int e = 0; e < 16; ++e) { yre[i][e] = 0.f; yim[i][e] = 0.f; }
    }

    // ---- staging helper (gload_lds: wave-uniform LDS base + lane*16) ----
    const int wubase = tid & ~63;
    auto stage_h = [&](unsigned short* dst, int blk) {
        const unsigned short* src = ht + blk * 16384;
        #pragma unroll
        for (int r = 0; r < 4; ++r) {
            const int idx = r * 512 + tid;          // 16B chunk 0..2047
            const int row = idx >> 4, cin = idx & 15;
            gload_lds16(src + row * 128 + ((cin ^ (row & 15)) << 3),
                        dst + ((r * 512 + wubase) << 3));
        }
    };

    // swizzled LDS fragment read: row in [0,128), chunk in [0,16)
    auto ldr = [&](const unsigned short* base, int row, int ch) -> bf16x8 {
        return *(const bf16x8*)(base + row * 128 + ((ch ^ (row & 15)) << 3));
    };

    // X fragments straight from the bf16 plane into registers.
    // xf[m2][ks]: A-frag rows h*64+m2*32+l31, K elems ks*16+hl*8 .. +8
    bf16x8 xf[2][8];
    auto load_xf = [&](const unsigned short* xp) {
        const unsigned short* base =
            xp + (size_t)(b * 1024 + p * 128 + h * 64 + l31) * 1024
               + q * 128 + hl * 8;
        #pragma unroll
        for (int m2 = 0; m2 < 2; ++m2)
            #pragma unroll
            for (int ks = 0; ks < 8; ++ks)
                xf[m2][ks] = *(const bf16x8*)(base + m2 * 32 * 1024 + ks * 16);
    };

    // ---- prologue: stage W(0), Lt(0); load X(g=0) ----
    stage_h(smem, rperm[0] * 8 + q);
    stage_h(smem + 32768, 0 * 8 + p);
    load_xf(xre);
    __syncthreads();

    #pragma unroll
    for (int cc = 0; cc < 8; ++cc) {
        const unsigned short* wb = smem + (cc & 1) * 16384;
        const unsigned short* lb = smem + 32768 + (cc & 1) * 16384;

        // issue next c's stages now; they drain at this c's END barrier
        // (the target buffers were last read in cc-1, before the previous
        // barrier, so writes are safe)
        if (cc < 7) {
            stage_h(smem + ((cc + 1) & 1) * 16384, rperm[cseq[cc + 1]] * 8 + q);
            stage_h(smem + 32768 + ((cc + 1) & 1) * 16384, cseq[cc + 1] * 8 + p);
        }

        // ---- stage A: u[m2] (32x32 C-frags), rows h*64+m2*32, cols wn*32
        f32x16 u[2];
        #pragma unroll
        for (int e = 0; e < 16; ++e) { u[0][e] = 0.f; u[1][e] = 0.f; }
        #pragma unroll
        for (int ks = 0; ks < 8; ++ks) {
            bf16x8 wfr = ldr(wb, wn * 32 + l31, 2 * ks + hl);
            u[0] = MFMA32(xf[0][ks], wfr, u[0]);
            u[1] = MFMA32(xf[1][ks], wfr, u[1]);
        }

        // reload X plane for g=1 (used from cc=4); WAR on xf keeps this
        // after stage A's last use, drains at this c's barrier
        if (cc == 3) load_xf(xim);

        // ---- stage B: Ypart += Lt_c . U  (K = this wave's 64 rows)
        #pragma unroll
        for (int t = 0; t < 4; ++t) {
            // B-frag for k-step t from C-frags u[t>>1] (verified R6):
            // pack pairs, exchange halves with shfl_xor(32)
            const int f = t >> 1, qa = (t & 1) * 2, qb = qa + 1;
            unsigned int lo0 = pk2(u[f][4 * qa + 0], u[f][4 * qa + 1]);
            unsigned int lo1 = pk2(u[f][4 * qa + 2], u[f][4 * qa + 3]);
            unsigned int hi0 = pk2(u[f][4 * qb + 0], u[f][4 * qb + 1]);
            unsigned int hi1 = pk2(u[f][4 * qb + 2], u[f][4 * qb + 3]);
            unsigned int sxl0 = (unsigned int)__shfl_xor((int)lo0, 32);
            unsigned int sxl1 = (unsigned int)__shfl_xor((int)lo1, 32);
            unsigned int sxh0 = (unsigned int)__shfl_xor((int)hi0, 32);
            unsigned int sxh1 = (unsigned int)__shfl_xor((int)hi1, 32);
            union { unsigned int d[4]; bf16x8 v; } ufu;
            ufu.d[0] = hl ? sxh0 : lo0;
            ufu.d[1] = hl ? sxh1 : lo1;
            ufu.d[2] = hl ? hi0 : sxl0;
            ufu.d[3] = hl ? hi1 : sxl1;
            #pragma unroll
            for (int mt = 0; mt < 4; ++mt) {
                bf16x8 lfr = ldr(lb, mt * 32 + l31, 8 * h + 2 * t + hl);
                if ((cc & 3) < 2) yre[mt] = MFMA32(lfr, ufu.v, yre[mt]);
                else              yim[mt] = MFMA32(lfr, ufu.v, yim[mt]);
            }
        }

        __syncthreads();   // single barrier per c: orders dbuf reuse and
                           // drains the stages issued at the top of this c
    }

    // ---- epilogue: sum split-K partials (h=1 dumps, h=0 adds + stores) ----
    float* red = (float*)smem + wn * 8192;   // 32 KB per wn group
    if (h == 1) {
        #pragma unroll
        for (int mt = 0; mt < 4; ++mt)
            #pragma unroll
            for (int q4 = 0; q4 < 4; ++q4) {
                f32x4 vr, vi;
                #pragma unroll
                for (int jj = 0; jj < 4; ++jj) {
                    vr[jj] = yre[mt][4 * q4 + jj];
                    vi[jj] = yim[mt][4 * q4 + jj];
                }
                *(f32x4*)(red + ((0 * 4 + mt) * 4 + q4) * 256 + lane * 4) = vr;
                *(f32x4*)(red + ((1 * 4 + mt) * 4 + q4) * 256 + lane * 4) = vi;
            }
    }
    __syncthreads();
    if (h == 0) {
        float2* o2 = (float2*)out;
        #pragma unroll
        for (int mt = 0; mt < 4; ++mt)
            #pragma unroll
            for (int q4 = 0; q4 < 4; ++q4) {
                f32x4 pr = *(const f32x4*)(red + ((0 * 4 + mt) * 4 + q4) * 256 + lane * 4);
                f32x4 pi = *(const f32x4*)(red + ((1 * 4 + mt) * 4 + q4) * 256 + lane * 4);
                #pragma unroll
                for (int jj = 0; jj < 4; ++jj) {
                    const int j = 4 * q4 + jj;
                    const int row = mt * 32 + (j & 3) + 8 * (j >> 2) + 4 * hl;
                    float2 v;
                    v.x = yre[mt][j] + pr[jj];
                    v.y = yim[mt][j] + pi[jj];
                    o2[(size_t)(b * 1024 + p * 128 + row) * 1024
                       + q * 128 + wn * 32 + l31] = v;
                }
            }
    }
}

extern "C" void kernel_launch(void* const* d_in, const int* in_sizes, int n_in,
                              void* d_out, int out_size, void* d_ws, size_t ws_size,
                              hipStream_t stream) {
    const float* x  = (const float*)d_in[0];
    const int* perm = (const int*)d_in[1];
    unsigned short* ws = (unsigned short*)d_ws;
    // workspace (ushort units): Ht 1M | Xre 4M | Xim 4M = 18 MB
    unsigned short* htp = ws;
    unsigned short* xre = ws + 1u * 1024u * 1024u;
    unsigned short* xim = ws + 5u * 1024u * 1024u;

    hipLaunchKernelGGL(prep_h, dim3(64), dim3(256), 0, stream,
        (const float*)d_in[2], (const float*)d_in[3], (const float*)d_in[4],
        (const float*)d_in[5], (const float*)d_in[6], (const float*)d_in[7],
        (const float*)d_in[8], (const float*)d_in[9], htp);
    hipLaunchKernelGGL(prep_x, dim3(4096), dim3(256), 0, stream,
        x, perm, xre, xim);
    hipLaunchKernelGGL(bilin_main, dim3(256), dim3(512), 0, stream,
        xre, xim, htp, (float*)d_out);
}

// Round 8
// 46.748 us; speedup vs baseline: 1.3359x; 1.3359x over previous
//
#include <hip/hip_runtime.h>
#include <hip/hip_bf16.h>
#include <stdint.h>

typedef __attribute__((ext_vector_type(8))) short bf16x8;
typedef __attribute__((ext_vector_type(4))) float f32x4;
typedef __attribute__((ext_vector_type(16))) float f32x16;

#define MFMA32(a, b, c) __builtin_amdgcn_mfma_f32_32x32x16_bf16((a), (b), (c), 0, 0, 0)

__device__ __forceinline__ unsigned short f2bf_rn(float f) {
    union { __bf16 b; unsigned short u; } v;
    v.b = (__bf16)f;
    return v.u;
}

// pack 2 floats -> 2 bf16 in a uint (compiler fuses to v_cvt_pk_bf16_f32)
__device__ __forceinline__ unsigned int pk2(float lo, float hi) {
    union { unsigned short s[2]; unsigned int u; } r;
    r.s[0] = f2bf_rn(lo); r.s[1] = f2bf_rn(hi);
    return r.u;
}

__device__ __forceinline__ void gload_lds16(const void* g, void* l) {
    __builtin_amdgcn_global_load_lds(
        (const __attribute__((address_space(1))) void*)g,
        (__attribute__((address_space(3))) void*)l, 16, 0, 0);
}

// ---------------------------------------------------------------------------
// prep_h: transpose each 128x128 fp32 block of the 8 H tensors to bf16.
//   ht[j][blk][k][r] = h_j[blk][r][k]   (j = input order hr1,hi1,...,hi4)
// Lt_c = ht[c], Wt_c = ht[rperm[c]].
// ---------------------------------------------------------------------------
__global__ __launch_bounds__(256) void prep_h(
    const float* __restrict__ h0, const float* __restrict__ h1,
    const float* __restrict__ h2, const float* __restrict__ h3,
    const float* __restrict__ h4, const float* __restrict__ h5,
    const float* __restrict__ h6, const float* __restrict__ h7,
    unsigned short* __restrict__ ht)
{
    const float* hmap[8] = {h0, h1, h2, h3, h4, h5, h6, h7};
    const int wg = blockIdx.x;        // 64 = j(8) x blk(8)
    const float* src = hmap[wg >> 3] + (wg & 7) * 16384;
    unsigned short* dst = ht + wg * 16384;
    __shared__ unsigned short tile[128 * 129];
    const int t = threadIdx.x;
    #pragma unroll 4
    for (int i = 0; i < 64; ++i) {
        int idx = t + 256 * i, r = idx >> 7, k = idx & 127;
        tile[r * 129 + k] = f2bf_rn(src[idx]);
    }
    __syncthreads();
    #pragma unroll 4
    for (int i = 0; i < 64; ++i) {
        int idx = t + 256 * i, k = idx >> 7, r = idx & 127;
        dst[idx] = tile[r * 129 + k];
    }
}

// ---------------------------------------------------------------------------
// prep_x: x (B,16,64,16,64,2) fp32 -> permuted bf16 planes Xre/Xim (B,1024,1024)
// ---------------------------------------------------------------------------
__global__ __launch_bounds__(256) void prep_x(
    const float* __restrict__ x, const int* __restrict__ perm,
    unsigned short* __restrict__ xre, unsigned short* __restrict__ xim)
{
    const int id = blockIdx.x * 256 + threadIdx.x;   // 4*1024*256 total
    const int b = id >> 18;
    const int row = (id >> 8) & 1023;
    const int col0 = (id & 255) * 4;
    const int n1 = perm[row >> 6], r1 = row & 63;
    const int n2 = perm[col0 >> 6], r2 = col0 & 63;
    const int src = (((b * 16 + n1) * 64 + r1) * 16 + n2) * 64 + r2;  // float2 units
    const float4* s = (const float4*)(x + src * 2);
    float4 v0 = s[0], v1 = s[1];
    ushort4 re, im;
    re.x = f2bf_rn(v0.x); re.y = f2bf_rn(v0.z); re.z = f2bf_rn(v1.x); re.w = f2bf_rn(v1.z);
    im.x = f2bf_rn(v0.y); im.y = f2bf_rn(v0.w); im.z = f2bf_rn(v1.y); im.w = f2bf_rn(v1.w);
    const int o = id * 4;
    *(ushort4*)(xre + o) = re;
    *(ushort4*)(xim + o) = im;
}

// ---------------------------------------------------------------------------
// bilin_main: 256 WGs = (b,p,q), q = bid&7 (XCD-locked). 512 threads = 8
// waves: wn = wid&3 (32-col group), h = wid>>2 (64-row half, split-K pair).
// 32x32x16 MFMA.  All operands staged via gload_lds into swizzled LDS.
// LDS = 160 KB (hw max): X 32K | W dbuf 2x32K | Lt dbuf 2x32K  ->
// ONE barrier per c-term: next-c W/Lt stages issue at the top of c and
// drain at c's END barrier (~2300 cyc of compute in between).  Only cc=3
// has an extra MID barrier so stage_x(im) can safely overwrite xlds.
// Per c: stage A  U[64x32] = X[h-rows] . W_c[:,wn-cols]
//        in-reg transpose (cvt-pack + shfl_xor(32), verified R6)
//        stage B  Ypart[128x32] += Lt_c[., h-rows] . U
// Epilogue sums the h=0/h=1 split-K partials through reused LDS.
// LDS swizzle: 16B chunk ch of row at LDS[row][ch] = G[row][ch ^ (row&15)].
// Register note (R7 lesson): y-accums = 128 unified regs; at 2 waves/SIMD
// the budget is 256/wave -> no persistent operand arrays in registers.
// ---------------------------------------------------------------------------
__global__ __launch_bounds__(512, 2) void bilin_main(
    const unsigned short* __restrict__ xre,
    const unsigned short* __restrict__ xim,
    const unsigned short* __restrict__ ht,
    float* __restrict__ out)
{
    const int wg = blockIdx.x;
    const int q = wg & 7, p = (wg >> 3) & 7, b = wg >> 6;
    const int tid = threadIdx.x;
    const int lane = tid & 63, wid = tid >> 6;
    const int wn = wid & 3, h = wid >> 2;
    const int l31 = lane & 31, hl = lane >> 5;

    __shared__ __align__(16) unsigned short smem[81920];   // 160 KB (hw max)
    unsigned short* xlds = smem;                      // 32 KB
    // W[par] = smem + 16384 + par*16384 ; L[par] = smem + 49152 + par*16384

    constexpr int cseq[8]  = {0, 1, 6, 7, 2, 3, 4, 5};
    constexpr int rperm[8] = {0, 1, 3, 2, 4, 5, 7, 6};

    f32x16 yre[4], yim[4];
    #pragma unroll
    for (int i = 0; i < 4; ++i) {
        #pragma unroll
        for (int e = 0; e < 16; ++e) { yre[i][e] = 0.f; yim[i][e] = 0.f; }
    }

    // ---- staging helpers (gload_lds: wave-uniform LDS base + lane*16) ----
    const int wubase = tid & ~63;
    auto stage_h = [&](unsigned short* dst, int blk) {
        const unsigned short* src = ht + blk * 16384;
        #pragma unroll
        for (int r = 0; r < 4; ++r) {
            const int idx = r * 512 + tid;          // 16B chunk 0..2047
            const int row = idx >> 4, cin = idx & 15;
            gload_lds16(src + row * 128 + ((cin ^ (row & 15)) << 3),
                        dst + ((r * 512 + wubase) << 3));
        }
    };
    auto stage_x = [&](const unsigned short* xp) {
        const unsigned short* src = xp + (size_t)(b * 1024 + p * 128) * 1024 + q * 128;
        #pragma unroll
        for (int r = 0; r < 4; ++r) {
            const int idx = r * 512 + tid;
            const int row = idx >> 4, cin = idx & 15;
            gload_lds16(src + row * 1024 + ((cin ^ (row & 15)) << 3),
                        xlds + ((r * 512 + wubase) << 3));
        }
    };

    // swizzled LDS fragment read: row in [0,128), chunk in [0,16)
    auto ldr = [&](const unsigned short* base, int row, int ch) -> bf16x8 {
        return *(const bf16x8*)(base + row * 128 + ((ch ^ (row & 15)) << 3));
    };

    // ---- prologue: stage W(0), Lt(0), X(g=0) ----
    stage_h(smem + 16384, rperm[0] * 8 + q);
    stage_h(smem + 49152, 0 * 8 + p);
    stage_x(xre);
    __syncthreads();

    #pragma unroll
    for (int cc = 0; cc < 8; ++cc) {
        const unsigned short* wb = smem + 16384 + (cc & 1) * 16384;
        const unsigned short* lb = smem + 49152 + (cc & 1) * 16384;

        // issue next c's W/Lt stages (opposite parity, last read in cc-1,
        // so writes are safe); they drain at this c's END barrier
        if (cc < 7) {
            stage_h(smem + 16384 + ((cc + 1) & 1) * 16384,
                    rperm[cseq[cc + 1]] * 8 + q);
            stage_h(smem + 49152 + ((cc + 1) & 1) * 16384,
                    cseq[cc + 1] * 8 + p);
        }

        // ---- stage A: u[m2] (32x32 C-frags), rows h*64+m2*32, cols wn*32
        f32x16 u[2];
        #pragma unroll
        for (int e = 0; e < 16; ++e) { u[0][e] = 0.f; u[1][e] = 0.f; }
        #pragma unroll
        for (int ks = 0; ks < 8; ++ks) {
            bf16x8 wfr = ldr(wb, wn * 32 + l31, 2 * ks + hl);
            #pragma unroll
            for (int m2 = 0; m2 < 2; ++m2) {
                bf16x8 xfr = ldr(xlds, h * 64 + m2 * 32 + l31, 2 * ks + hl);
                u[m2] = MFMA32(xfr, wfr, u[m2]);
            }
        }

        // g switch: all waves are now done reading X(re); restage X(im).
        // MID barrier protects the xlds overwrite; stage drains at END.
        if (cc == 3) {
            __syncthreads();
            stage_x(xim);
        }

        // ---- stage B: Ypart += Lt_c . U  (K = this wave's 64 rows)
        #pragma unroll
        for (int t = 0; t < 4; ++t) {
            // B-frag for k-step t from C-frags u[t>>1] (verified R6):
            // pack pairs, exchange halves with shfl_xor(32)
            const int f = t >> 1, qa = (t & 1) * 2, qb = qa + 1;
            unsigned int lo0 = pk2(u[f][4 * qa + 0], u[f][4 * qa + 1]);
            unsigned int lo1 = pk2(u[f][4 * qa + 2], u[f][4 * qa + 3]);
            unsigned int hi0 = pk2(u[f][4 * qb + 0], u[f][4 * qb + 1]);
            unsigned int hi1 = pk2(u[f][4 * qb + 2], u[f][4 * qb + 3]);
            unsigned int sxl0 = (unsigned int)__shfl_xor((int)lo0, 32);
            unsigned int sxl1 = (unsigned int)__shfl_xor((int)lo1, 32);
            unsigned int sxh0 = (unsigned int)__shfl_xor((int)hi0, 32);
            unsigned int sxh1 = (unsigned int)__shfl_xor((int)hi1, 32);
            union { unsigned int d[4]; bf16x8 v; } ufu;
            ufu.d[0] = hl ? sxh0 : lo0;
            ufu.d[1] = hl ? sxh1 : lo1;
            ufu.d[2] = hl ? hi0 : sxl0;
            ufu.d[3] = hl ? hi1 : sxl1;
            #pragma unroll
            for (int mt = 0; mt < 4; ++mt) {
                bf16x8 lfr = ldr(lb, mt * 32 + l31, 8 * h + 2 * t + hl);
                if ((cc & 3) < 2) yre[mt] = MFMA32(lfr, ufu.v, yre[mt]);
                else              yim[mt] = MFMA32(lfr, ufu.v, yim[mt]);
            }
        }

        __syncthreads();   // END: orders dbuf parity reuse; drains the
                           // stages issued at the top of this c (and the
                           // cc=3 X restage)
    }

    // ---- epilogue: sum split-K partials (h=1 dumps, h=0 adds + stores) ----
    float* red = (float*)smem + wn * 8192;   // 4 groups x 32 KB = 128 KB
    if (h == 1) {
        #pragma unroll
        for (int mt = 0; mt < 4; ++mt)
            #pragma unroll
            for (int q4 = 0; q4 < 4; ++q4) {
                f32x4 vr, vi;
                #pragma unroll
                for (int jj = 0; jj < 4; ++jj) {
                    vr[jj] = yre[mt][4 * q4 + jj];
                    vi[jj] = yim[mt][4 * q4 + jj];
                }
                *(f32x4*)(red + ((0 * 4 + mt) * 4 + q4) * 256 + lane * 4) = vr;
                *(f32x4*)(red + ((1 * 4 + mt) * 4 + q4) * 256 + lane * 4) = vi;
            }
    }
    __syncthreads();
    if (h == 0) {
        float2* o2 = (float2*)out;
        #pragma unroll
        for (int mt = 0; mt < 4; ++mt)
            #pragma unroll
            for (int q4 = 0; q4 < 4; ++q4) {
                f32x4 pr = *(const f32x4*)(red + ((0 * 4 + mt) * 4 + q4) * 256 + lane * 4);
                f32x4 pi = *(const f32x4*)(red + ((1 * 4 + mt) * 4 + q4) * 256 + lane * 4);
                #pragma unroll
                for (int jj = 0; jj < 4; ++jj) {
                    const int j = 4 * q4 + jj;
                    const int row = mt * 32 + (j & 3) + 8 * (j >> 2) + 4 * hl;
                    float2 v;
                    v.x = yre[mt][j] + pr[jj];
                    v.y = yim[mt][j] + pi[jj];
                    o2[(size_t)(b * 1024 + p * 128 + row) * 1024
                       + q * 128 + wn * 32 + l31] = v;
                }
            }
    }
}

extern "C" void kernel_launch(void* const* d_in, const int* in_sizes, int n_in,
                              void* d_out, int out_size, void* d_ws, size_t ws_size,
                              hipStream_t stream) {
    const float* x  = (const float*)d_in[0];
    const int* perm = (const int*)d_in[1];
    unsigned short* ws = (unsigned short*)d_ws;
    // workspace (ushort units): Ht 1M | Xre 4M | Xim 4M = 18 MB
    unsigned short* htp = ws;
    unsigned short* xre = ws + 1u * 1024u * 1024u;
    unsigned short* xim = ws + 5u * 1024u * 1024u;

    hipLaunchKernelGGL(prep_h, dim3(64), dim3(256), 0, stream,
        (const float*)d_in[2], (const float*)d_in[3], (const float*)d_in[4],
        (const float*)d_in[5], (const float*)d_in[6], (const float*)d_in[7],
        (const float*)d_in[8], (const float*)d_in[9], htp);
    hipLaunchKernelGGL(prep_x, dim3(4096), dim3(256), 0, stream,
        x, perm, xre, xim);
    hipLaunchKernelGGL(bilin_main, dim3(256), dim3(512), 0, stream,
        xre, xim, htp, (float*)d_out);
}

// Round 9
// 42.477 us; speedup vs baseline: 1.4703x; 1.1006x over previous
//
#include <hip/hip_runtime.h>
#include <hip/hip_bf16.h>
#include <stdint.h>

typedef __attribute__((ext_vector_type(8))) short bf16x8;
typedef __attribute__((ext_vector_type(4))) float f32x4;
typedef __attribute__((ext_vector_type(16))) float f32x16;

#define MFMA32(a, b, c) __builtin_amdgcn_mfma_f32_32x32x16_bf16((a), (b), (c), 0, 0, 0)

__device__ __forceinline__ unsigned short f2bf_rn(float f) {
    union { __bf16 b; unsigned short u; } v;
    v.b = (__bf16)f;
    return v.u;
}

// pack 2 floats -> 2 bf16 in a uint (compiler fuses to v_cvt_pk_bf16_f32)
__device__ __forceinline__ unsigned int pk2(float lo, float hi) {
    union { unsigned short s[2]; unsigned int u; } r;
    r.s[0] = f2bf_rn(lo); r.s[1] = f2bf_rn(hi);
    return r.u;
}

__device__ __forceinline__ void gload_lds16(const void* g, void* l) {
    __builtin_amdgcn_global_load_lds(
        (const __attribute__((address_space(1))) void*)g,
        (__attribute__((address_space(3))) void*)l, 16, 0, 0);
}

// ---------------------------------------------------------------------------
// prep_h: transpose each 128x128 fp32 block of the 8 H tensors to bf16.
//   ht[j][blk][k][r] = h_j[blk][r][k]   (j = input order hr1,hi1,...,hi4)
// Lt_c = ht[c], Wt_c = ht[rperm[c]].
// ---------------------------------------------------------------------------
__global__ __launch_bounds__(256) void prep_h(
    const float* __restrict__ h0, const float* __restrict__ h1,
    const float* __restrict__ h2, const float* __restrict__ h3,
    const float* __restrict__ h4, const float* __restrict__ h5,
    const float* __restrict__ h6, const float* __restrict__ h7,
    unsigned short* __restrict__ ht)
{
    const float* hmap[8] = {h0, h1, h2, h3, h4, h5, h6, h7};
    const int wg = blockIdx.x;        // 64 = j(8) x blk(8)
    const float* src = hmap[wg >> 3] + (wg & 7) * 16384;
    unsigned short* dst = ht + wg * 16384;
    __shared__ unsigned short tile[128 * 129];
    const int t = threadIdx.x;
    #pragma unroll 4
    for (int i = 0; i < 64; ++i) {
        int idx = t + 256 * i, r = idx >> 7, k = idx & 127;
        tile[r * 129 + k] = f2bf_rn(src[idx]);
    }
    __syncthreads();
    #pragma unroll 4
    for (int i = 0; i < 64; ++i) {
        int idx = t + 256 * i, k = idx >> 7, r = idx & 127;
        dst[idx] = tile[r * 129 + k];
    }
}

// ---------------------------------------------------------------------------
// bilin_main (prep_x FUSED): 256 WGs = (b,p,q), q = bid&7 (XCD-locked).
// 512 threads = 8 waves: wn = wid&3 (32-col group), h = wid>>2 (64-row half,
// split-K pair). 32x32x16 MFMA.
// Prologue stages this WG's 128x128 X tile DIRECTLY from the fp32 input
// (permutation applied in the address, convert in flight) into TWO resident
// LDS planes (re+im, 64 KB) — the prep_x kernel and its 50 MB HBM round
// trip are gone.  W double-buffered (64 KB), Lt single-buffered (32 KB):
// exactly 160 KB.  R6-verified 2-barrier schedule: every staged buffer gets
// a full compute stage between issue and its draining barrier.
// Per c: stage A  U[64x32] = X[h-rows] . W_c[:,wn-cols]
//        [MID barrier]  (drains Lt_c, issued at END of cc-1)
//        issue W_{c+1}
//        in-reg transpose (cvt-pack + shfl_xor(32), verified R6)
//        stage B  Ypart[128x32] += Lt_c[., h-rows] . U
//        [END barrier]  (drains W_{c+1})
//        issue Lt_{c+1}
// Epilogue sums the h=0/h=1 split-K partials through reused LDS.
// LDS swizzle: 16B chunk ch of row at LDS[row][ch] = G[row][ch ^ (row&15)].
// Register note (R7 lesson): y-accums = 128 unified regs; no persistent
// operand arrays in registers (prologue X transients die before the loop).
// ---------------------------------------------------------------------------
__global__ __launch_bounds__(512, 2) void bilin_main(
    const float* __restrict__ x, const int* __restrict__ perm,
    const unsigned short* __restrict__ ht, float* __restrict__ out)
{
    const int wg = blockIdx.x;
    const int q = wg & 7, p = (wg >> 3) & 7, b = wg >> 6;
    const int tid = threadIdx.x;
    const int lane = tid & 63, wid = tid >> 6;
    const int wn = wid & 3, h = wid >> 2;
    const int l31 = lane & 31, hl = lane >> 5;

    __shared__ __align__(16) unsigned short smem[81920];   // 160 KB (hw max)
    unsigned short* xre_lds = smem;                        // 32 KB
    unsigned short* xim_lds = smem + 16384;                // 32 KB
    // W[par] = smem + 32768 + par*16384 (64 KB) ; Lt = smem + 65536 (32 KB)
    unsigned short* llds = smem + 65536;

    constexpr int cseq[8]  = {0, 1, 6, 7, 2, 3, 4, 5};
    constexpr int rperm[8] = {0, 1, 3, 2, 4, 5, 7, 6};

    // ---- staging helpers (gload_lds: wave-uniform LDS base + lane*16) ----
    const int wubase = tid & ~63;
    auto stage_h = [&](unsigned short* dst, int blk) {
        const unsigned short* src = ht + blk * 16384;
        #pragma unroll
        for (int r = 0; r < 4; ++r) {
            const int idx = r * 512 + tid;          // 16B chunk 0..2047
            const int row = idx >> 4, cin = idx & 15;
            gload_lds16(src + row * 128 + ((cin ^ (row & 15)) << 3),
                        dst + ((r * 512 + wubase) << 3));
        }
    };

    // swizzled LDS fragment read: row in [0,128), chunk in [0,16)
    auto ldr = [&](const unsigned short* base, int row, int ch) -> bf16x8 {
        return *(const bf16x8*)(base + row * 128 + ((ch ^ (row & 15)) << 3));
    };

    // ---- prologue ----
    // 1) issue this WG's X-tile fp32 loads (16 x float4 per thread)
    //    thread (i,tid): row = (i*512+tid)>>4 in [0,128), chunk cin = &15
    float4 xv[4][4];
    int woffs[4];
    #pragma unroll
    for (int i = 0; i < 4; ++i) {
        const int idx = i * 512 + tid;
        const int row = idx >> 4, cin = idx & 15;
        const int n1 = perm[2 * p + (row >> 6)];       // wave-uniform
        const int n2 = perm[2 * q + (cin >> 3)];
        const int r1 = row & 63, r2 = (cin & 7) * 8;
        const float* sp = x + ((size_t)((b * 16 + n1) * 64 + r1) * 1024
                               + n2 * 64 + r2) * 2;
        #pragma unroll
        for (int j = 0; j < 4; ++j)
            xv[i][j] = *(const float4*)(sp + j * 4);
        woffs[i] = row * 128 + ((cin ^ (row & 15)) << 3);
    }
    // 2) issue W(0), Lt(0) async stages
    stage_h(smem + 32768, rperm[0] * 8 + q);
    stage_h(llds, 0 * 8 + p);
    // 3) convert + write X planes (waits only on the fp32 loads)
    #pragma unroll
    for (int i = 0; i < 4; ++i) {
        bf16x8 re, im;
        #pragma unroll
        for (int j = 0; j < 4; ++j) {
            re[2 * j]     = (short)f2bf_rn(xv[i][j].x);
            re[2 * j + 1] = (short)f2bf_rn(xv[i][j].z);
            im[2 * j]     = (short)f2bf_rn(xv[i][j].y);
            im[2 * j + 1] = (short)f2bf_rn(xv[i][j].w);
        }
        *(bf16x8*)(xre_lds + woffs[i]) = re;
        *(bf16x8*)(xim_lds + woffs[i]) = im;
    }
    __syncthreads();   // drains gloads + orders X writes

    f32x16 yre[4], yim[4];
    #pragma unroll
    for (int i = 0; i < 4; ++i) {
        #pragma unroll
        for (int e = 0; e < 16; ++e) { yre[i][e] = 0.f; yim[i][e] = 0.f; }
    }

    #pragma unroll
    for (int cc = 0; cc < 8; ++cc) {
        const unsigned short* wb = smem + 32768 + (cc & 1) * 16384;
        const unsigned short* xg = (cc < 4) ? xre_lds : xim_lds;

        // ---- stage A: u[m2] (32x32 C-frags), rows h*64+m2*32, cols wn*32
        f32x16 u[2];
        #pragma unroll
        for (int e = 0; e < 16; ++e) { u[0][e] = 0.f; u[1][e] = 0.f; }
        #pragma unroll
        for (int ks = 0; ks < 8; ++ks) {
            bf16x8 wfr = ldr(wb, wn * 32 + l31, 2 * ks + hl);
            #pragma unroll
            for (int m2 = 0; m2 < 2; ++m2) {
                bf16x8 xfr = ldr(xg, h * 64 + m2 * 32 + l31, 2 * ks + hl);
                u[m2] = MFMA32(xfr, wfr, u[m2]);
            }
        }

        __syncthreads();   // MID: drains Lt_c (issued at END of cc-1)
        if (cc < 7)        // W_{c+1}: opposite parity, last read in cc-1
            stage_h(smem + 32768 + ((cc + 1) & 1) * 16384,
                    rperm[cseq[cc + 1]] * 8 + q);

        // ---- stage B: Ypart += Lt_c . U  (K = this wave's 64 rows)
        #pragma unroll
        for (int t = 0; t < 4; ++t) {
            // B-frag for k-step t from C-frags u[t>>1] (verified R6):
            // pack pairs, exchange halves with shfl_xor(32)
            const int f = t >> 1, qa = (t & 1) * 2, qb = qa + 1;
            unsigned int lo0 = pk2(u[f][4 * qa + 0], u[f][4 * qa + 1]);
            unsigned int lo1 = pk2(u[f][4 * qa + 2], u[f][4 * qa + 3]);
            unsigned int hi0 = pk2(u[f][4 * qb + 0], u[f][4 * qb + 1]);
            unsigned int hi1 = pk2(u[f][4 * qb + 2], u[f][4 * qb + 3]);
            unsigned int sxl0 = (unsigned int)__shfl_xor((int)lo0, 32);
            unsigned int sxl1 = (unsigned int)__shfl_xor((int)lo1, 32);
            unsigned int sxh0 = (unsigned int)__shfl_xor((int)hi0, 32);
            unsigned int sxh1 = (unsigned int)__shfl_xor((int)hi1, 32);
            union { unsigned int d[4]; bf16x8 v; } ufu;
            ufu.d[0] = hl ? sxh0 : lo0;
            ufu.d[1] = hl ? sxh1 : lo1;
            ufu.d[2] = hl ? hi0 : sxl0;
            ufu.d[3] = hl ? hi1 : sxl1;
            #pragma unroll
            for (int mt = 0; mt < 4; ++mt) {
                bf16x8 lfr = ldr(llds, mt * 32 + l31, 8 * h + 2 * t + hl);
                if ((cc & 3) < 2) yre[mt] = MFMA32(lfr, ufu.v, yre[mt]);
                else              yim[mt] = MFMA32(lfr, ufu.v, yim[mt]);
            }
        }

        __syncthreads();   // END: all waves done reading llds; drains W_{c+1}
        if (cc < 7)
            stage_h(llds, cseq[cc + 1] * 8 + p);   // drains at MID of cc+1
    }

    // ---- epilogue: sum split-K partials (h=1 dumps, h=0 adds + stores) ----
    float* red = (float*)smem + wn * 8192;   // 4 groups x 32 KB = 128 KB
    if (h == 1) {
        #pragma unroll
        for (int mt = 0; mt < 4; ++mt)
            #pragma unroll
            for (int q4 = 0; q4 < 4; ++q4) {
                f32x4 vr, vi;
                #pragma unroll
                for (int jj = 0; jj < 4; ++jj) {
                    vr[jj] = yre[mt][4 * q4 + jj];
                    vi[jj] = yim[mt][4 * q4 + jj];
                }
                *(f32x4*)(red + ((0 * 4 + mt) * 4 + q4) * 256 + lane * 4) = vr;
                *(f32x4*)(red + ((1 * 4 + mt) * 4 + q4) * 256 + lane * 4) = vi;
            }
    }
    __syncthreads();
    if (h == 0) {
        float2* o2 = (float2*)out;
        #pragma unroll
        for (int mt = 0; mt < 4; ++mt)
            #pragma unroll
            for (int q4 = 0; q4 < 4; ++q4) {
                f32x4 pr = *(const f32x4*)(red + ((0 * 4 + mt) * 4 + q4) * 256 + lane * 4);
                f32x4 pi = *(const f32x4*)(red + ((1 * 4 + mt) * 4 + q4) * 256 + lane * 4);
                #pragma unroll
                for (int jj = 0; jj < 4; ++jj) {
                    const int j = 4 * q4 + jj;
                    const int row = mt * 32 + (j & 3) + 8 * (j >> 2) + 4 * hl;
                    float2 v;
                    v.x = yre[mt][j] + pr[jj];
                    v.y = yim[mt][j] + pi[jj];
                    o2[(size_t)(b * 1024 + p * 128 + row) * 1024
                       + q * 128 + wn * 32 + l31] = v;
                }
            }
    }
}

extern "C" void kernel_launch(void* const* d_in, const int* in_sizes, int n_in,
                              void* d_out, int out_size, void* d_ws, size_t ws_size,
                              hipStream_t stream) {
    const float* x  = (const float*)d_in[0];
    const int* perm = (const int*)d_in[1];
    unsigned short* htp = (unsigned short*)d_ws;   // 2 MB

    hipLaunchKernelGGL(prep_h, dim3(64), dim3(256), 0, stream,
        (const float*)d_in[2], (const float*)d_in[3], (const float*)d_in[4],
        (const float*)d_in[5], (const float*)d_in[6], (const float*)d_in[7],
        (const float*)d_in[8], (const float*)d_in[9], htp);
    hipLaunchKernelGGL(bilin_main, dim3(256), dim3(512), 0, stream,
        x, perm, htp, (float*)d_out);
}

// Round 10
// 40.177 us; speedup vs baseline: 1.5544x; 1.0572x over previous
//
#include <hip/hip_runtime.h>
#include <hip/hip_bf16.h>
#include <stdint.h>

typedef __attribute__((ext_vector_type(8))) short bf16x8;
typedef __attribute__((ext_vector_type(4))) float f32x4;
typedef __attribute__((ext_vector_type(16))) float f32x16;

#define MFMA32(a, b, c) __builtin_amdgcn_mfma_f32_32x32x16_bf16((a), (b), (c), 0, 0, 0)

__device__ __forceinline__ unsigned short f2bf_rn(float f) {
    union { __bf16 b; unsigned short u; } v;
    v.b = (__bf16)f;
    return v.u;
}

// pack 2 floats -> 2 bf16 in a uint (compiler fuses to v_cvt_pk_bf16_f32)
__device__ __forceinline__ unsigned int pk2(float lo, float hi) {
    union { unsigned short s[2]; unsigned int u; } r;
    r.s[0] = f2bf_rn(lo); r.s[1] = f2bf_rn(hi);
    return r.u;
}

__device__ __forceinline__ void gload_lds16(const void* g, void* l) {
    __builtin_amdgcn_global_load_lds(
        (const __attribute__((address_space(1))) void*)g,
        (__attribute__((address_space(3))) void*)l, 16, 0, 0);
}

// ---------------------------------------------------------------------------
// prep_h: transpose each 128x128 fp32 block of the 8 H tensors to bf16.
//   ht[j][blk][k][r] = h_j[blk][r][k]   (j = input order hr1,hi1,...,hi4)
// 256 WGs = jblk(64) x k-quarter(4): 4x the parallelism of the R9 version.
// ---------------------------------------------------------------------------
__global__ __launch_bounds__(256) void prep_h(
    const float* __restrict__ h0, const float* __restrict__ h1,
    const float* __restrict__ h2, const float* __restrict__ h3,
    const float* __restrict__ h4, const float* __restrict__ h5,
    const float* __restrict__ h6, const float* __restrict__ h7,
    unsigned short* __restrict__ ht)
{
    const float* hmap[8] = {h0, h1, h2, h3, h4, h5, h6, h7};
    const int wg = blockIdx.x;            // 256 = jblk(64) x quarter(4)
    const int jblk = wg >> 2, qt = wg & 3;
    const float* src = hmap[jblk >> 3] + (jblk & 7) * 16384;
    unsigned short* dst = ht + jblk * 16384;
    __shared__ unsigned short tile[32 * 129];
    const int t = threadIdx.x;
    #pragma unroll
    for (int i = 0; i < 16; ++i) {
        int idx = t + 256 * i;            // 4096 = r(128) x kk(32)
        int r = idx >> 5, kk = idx & 31;
        tile[kk * 129 + r] = f2bf_rn(src[r * 128 + qt * 32 + kk]);
    }
    __syncthreads();
    #pragma unroll
    for (int i = 0; i < 16; ++i) {
        int idx = t + 256 * i;            // 4096 = k(32) x r(128)
        int k = idx >> 7, r = idx & 127;
        dst[(qt * 32 + k) * 128 + r] = tile[k * 129 + r];
    }
}

// ---------------------------------------------------------------------------
// bilin_main: 256 WGs = (b,p,q), q = bid&7 (XCD-locked). 512 threads = 8
// waves: wn = wid&3 (32-col group), h = wid>>2 (64-row half, split-K pair).
// 32x32x16 MFMA.  prep_x fused: the WG's 128x128 X tile is read straight
// from the fp32 input (perm in the address, convert in flight) into ONE
// resident LDS plane; Xim restaged inline at cc=3.
// LDS = 160 KB exact: X 32K | W dbuf 2x32K | Lt dbuf 2x32K  ->  ONE barrier
// per c-term (R8 schedule): W_{c+1} and Lt_{c+1} issue at the TOP of c and
// drain at c's END barrier, a full c-term (~1400 cyc) later.
// Per c: [issue next W/Lt] -> stage A  U[64x32] = X[h-rows].W_c[:,wn-cols]
//        -> in-reg transpose (2-shfl form of the R6-verified exchange)
//        -> stage B  Ypart[128x32] += Lt_c[., h-rows].U  -> [END barrier]
// cc=3 adds one mid barrier + inline Xim restage after stage B.
// Epilogue sums the h=0/h=1 split-K partials through reused LDS.
// LDS swizzle: 16B chunk ch of row at LDS[row][ch] = G[row][ch ^ (row&15)].
// Register note (R7 lesson): y-accums = 128 unified regs; no persistent
// operand arrays in registers (X transients are barrier-local).
// ---------------------------------------------------------------------------
__global__ __launch_bounds__(512, 2) void bilin_main(
    const float* __restrict__ x, const int* __restrict__ perm,
    const unsigned short* __restrict__ ht, float* __restrict__ out)
{
    const int wg = blockIdx.x;
    const int q = wg & 7, p = (wg >> 3) & 7, b = wg >> 6;
    const int tid = threadIdx.x;
    const int lane = tid & 63, wid = tid >> 6;
    const int wn = wid & 3, h = wid >> 2;
    const int l31 = lane & 31, hl = lane >> 5;

    __shared__ __align__(16) unsigned short smem[81920];   // 160 KB (hw max)
    unsigned short* xlds = smem;                           // 32 KB, 1 plane
    // W[par] = smem + 16384 + par*16384 ; Lt[par] = smem + 49152 + par*16384

    constexpr int cseq[8]  = {0, 1, 6, 7, 2, 3, 4, 5};
    constexpr int rperm[8] = {0, 1, 3, 2, 4, 5, 7, 6};

    const int n1a = perm[2 * p], n1b = perm[2 * p + 1];
    const int n2a = perm[2 * q], n2b = perm[2 * q + 1];

    // ---- staging helpers (gload_lds: wave-uniform LDS base + lane*16) ----
    const int wubase = tid & ~63;
    auto stage_h = [&](unsigned short* dst, int blk) {
        const unsigned short* src = ht + blk * 16384;
        #pragma unroll
        for (int r = 0; r < 4; ++r) {
            const int idx = r * 512 + tid;          // 16B chunk 0..2047
            const int row = idx >> 4, cin = idx & 15;
            gload_lds16(src + row * 128 + ((cin ^ (row & 15)) << 3),
                        dst + ((r * 512 + wubase) << 3));
        }
    };

    // fused prep_x: fp32 loads -> convert -> swizzled LDS plane write
    auto stage_x = [&](int g) {
        float4 xv[4][4];
        int woffs[4];
        #pragma unroll
        for (int i = 0; i < 4; ++i) {
            const int idx = i * 512 + tid;
            const int row = idx >> 4, cin = idx & 15;
            const int n1 = (i >> 1) ? n1b : n1a;       // row>>6 == i>>1
            const int n2 = (cin >> 3) ? n2b : n2a;
            const int r1 = row & 63, r2 = (cin & 7) * 8;
            const float* sp = x + ((size_t)((b * 16 + n1) * 64 + r1) * 1024
                                   + n2 * 64 + r2) * 2;
            #pragma unroll
            for (int j = 0; j < 4; ++j)
                xv[i][j] = *(const float4*)(sp + j * 4);
            woffs[i] = row * 128 + ((cin ^ (row & 15)) << 3);
        }
        #pragma unroll
        for (int i = 0; i < 4; ++i) {
            bf16x8 t;
            #pragma unroll
            for (int j = 0; j < 4; ++j) {
                if (g == 0) {
                    t[2 * j]     = (short)f2bf_rn(xv[i][j].x);
                    t[2 * j + 1] = (short)f2bf_rn(xv[i][j].z);
                } else {
                    t[2 * j]     = (short)f2bf_rn(xv[i][j].y);
                    t[2 * j + 1] = (short)f2bf_rn(xv[i][j].w);
                }
            }
            *(bf16x8*)(xlds + woffs[i]) = t;
        }
    };

    // swizzled LDS fragment read: row in [0,128), chunk in [0,16)
    auto ldr = [&](const unsigned short* base, int row, int ch) -> bf16x8 {
        return *(const bf16x8*)(base + row * 128 + ((ch ^ (row & 15)) << 3));
    };

    // ---- prologue: stage W(0), Lt(0) async; X(g=0) via registers ----
    stage_h(smem + 16384, rperm[0] * 8 + q);
    stage_h(smem + 49152, 0 * 8 + p);
    stage_x(0);
    __syncthreads();

    f32x16 yre[4], yim[4];
    #pragma unroll
    for (int i = 0; i < 4; ++i) {
        #pragma unroll
        for (int e = 0; e < 16; ++e) { yre[i][e] = 0.f; yim[i][e] = 0.f; }
    }

    #pragma unroll
    for (int cc = 0; cc < 8; ++cc) {
        const unsigned short* wb = smem + 16384 + (cc & 1) * 16384;
        const unsigned short* lb = smem + 49152 + (cc & 1) * 16384;

        // issue next c's W/Lt stages (opposite parity, last read in cc-1
        // before END(cc-1) -> safe); they drain at this c's END barrier
        if (cc < 7) {
            stage_h(smem + 16384 + ((cc + 1) & 1) * 16384,
                    rperm[cseq[cc + 1]] * 8 + q);
            stage_h(smem + 49152 + ((cc + 1) & 1) * 16384,
                    cseq[cc + 1] * 8 + p);
        }

        // ---- stage A: u[m2] (32x32 C-frags), rows h*64+m2*32, cols wn*32
        f32x16 u[2];
        #pragma unroll
        for (int e = 0; e < 16; ++e) { u[0][e] = 0.f; u[1][e] = 0.f; }
        #pragma unroll
        for (int ks = 0; ks < 8; ++ks) {
            bf16x8 wfr = ldr(wb, wn * 32 + l31, 2 * ks + hl);
            #pragma unroll
            for (int m2 = 0; m2 < 2; ++m2) {
                bf16x8 xfr = ldr(xlds, h * 64 + m2 * 32 + l31, 2 * ks + hl);
                u[m2] = MFMA32(xfr, wfr, u[m2]);
            }
        }

        // ---- stage B: Ypart += Lt_c . U  (K = this wave's 64 rows)
        #pragma unroll
        for (int t = 0; t < 4; ++t) {
            // B-frag for k-step t from C-frags u[t>>1]: 2-shfl form of the
            // R6-verified exchange (pre-select what the partner needs).
            const int f = t >> 1, qa = (t & 1) * 2, qb = qa + 1;
            unsigned int lo0 = pk2(u[f][4 * qa + 0], u[f][4 * qa + 1]);
            unsigned int lo1 = pk2(u[f][4 * qa + 2], u[f][4 * qa + 3]);
            unsigned int hi0 = pk2(u[f][4 * qb + 0], u[f][4 * qb + 1]);
            unsigned int hi1 = pk2(u[f][4 * qb + 2], u[f][4 * qb + 3]);
            unsigned int send0 = hl ? lo0 : hi0;
            unsigned int send1 = hl ? lo1 : hi1;
            unsigned int sx0 = (unsigned int)__shfl_xor((int)send0, 32);
            unsigned int sx1 = (unsigned int)__shfl_xor((int)send1, 32);
            union { unsigned int d[4]; bf16x8 v; } ufu;
            ufu.d[0] = hl ? sx0 : lo0;
            ufu.d[1] = hl ? sx1 : lo1;
            ufu.d[2] = hl ? hi0 : sx0;
            ufu.d[3] = hl ? hi1 : sx1;
            #pragma unroll
            for (int mt = 0; mt < 4; ++mt) {
                bf16x8 lfr = ldr(lb, mt * 32 + l31, 8 * h + 2 * t + hl);
                if ((cc & 3) < 2) yre[mt] = MFMA32(lfr, ufu.v, yre[mt]);
                else              yim[mt] = MFMA32(lfr, ufu.v, yim[mt]);
            }
        }

        // g switch: all waves done reading X(re) after their stage A; the
        // mid barrier orders the xlds overwrite, restage lands before END.
        if (cc == 3) {
            __syncthreads();
            stage_x(1);
        }

        __syncthreads();   // END: orders dbuf parity reuse; drains the
                           // W/Lt stages issued at the top of this c
    }

    // ---- epilogue: sum split-K partials (h=1 dumps, h=0 adds + stores) ----
    float* red = (float*)smem + wn * 8192;   // 4 groups x 32 KB = 128 KB
    if (h == 1) {
        #pragma unroll
        for (int mt = 0; mt < 4; ++mt)
            #pragma unroll
            for (int q4 = 0; q4 < 4; ++q4) {
                f32x4 vr, vi;
                #pragma unroll
                for (int jj = 0; jj < 4; ++jj) {
                    vr[jj] = yre[mt][4 * q4 + jj];
                    vi[jj] = yim[mt][4 * q4 + jj];
                }
                *(f32x4*)(red + ((0 * 4 + mt) * 4 + q4) * 256 + lane * 4) = vr;
                *(f32x4*)(red + ((1 * 4 + mt) * 4 + q4) * 256 + lane * 4) = vi;
            }
    }
    __syncthreads();
    if (h == 0) {
        float2* o2 = (float2*)out;
        #pragma unroll
        for (int mt = 0; mt < 4; ++mt)
            #pragma unroll
            for (int q4 = 0; q4 < 4; ++q4) {
                f32x4 pr = *(const f32x4*)(red + ((0 * 4 + mt) * 4 + q4) * 256 + lane * 4);
                f32x4 pi = *(const f32x4*)(red + ((1 * 4 + mt) * 4 + q4) * 256 + lane * 4);
                #pragma unroll
                for (int jj = 0; jj < 4; ++jj) {
                    const int j = 4 * q4 + jj;
                    const int row = mt * 32 + (j & 3) + 8 * (j >> 2) + 4 * hl;
                    float2 v;
                    v.x = yre[mt][j] + pr[jj];
                    v.y = yim[mt][j] + pi[jj];
                    o2[(size_t)(b * 1024 + p * 128 + row) * 1024
                       + q * 128 + wn * 32 + l31] = v;
                }
            }
    }
}

extern "C" void kernel_launch(void* const* d_in, const int* in_sizes, int n_in,
                              void* d_out, int out_size, void* d_ws, size_t ws_size,
                              hipStream_t stream) {
    const float* x  = (const float*)d_in[0];
    const int* perm = (const int*)d_in[1];
    unsigned short* htp = (unsigned short*)d_ws;   // 2 MB

    hipLaunchKernelGGL(prep_h, dim3(256), dim3(256), 0, stream,
        (const float*)d_in[2], (const float*)d_in[3], (const float*)d_in[4],
        (const float*)d_in[5], (const float*)d_in[6], (const float*)d_in[7],
        (const float*)d_in[8], (const float*)d_in[9], htp);
    hipLaunchKernelGGL(bilin_main, dim3(256), dim3(512), 0, stream,
        x, perm, htp, (float*)d_out);
}

// Round 11
// 39.483 us; speedup vs baseline: 1.5818x; 1.0176x over previous
//
#include <hip/hip_runtime.h>
#include <hip/hip_bf16.h>
#include <stdint.h>

typedef __attribute__((ext_vector_type(8))) short bf16x8;
typedef __attribute__((ext_vector_type(4))) float f32x4;
typedef __attribute__((ext_vector_type(16))) float f32x16;

#define MFMA32(a, b, c) __builtin_amdgcn_mfma_f32_32x32x16_bf16((a), (b), (c), 0, 0, 0)

__device__ __forceinline__ unsigned short f2bf_rn(float f) {
    union { __bf16 b; unsigned short u; } v;
    v.b = (__bf16)f;
    return v.u;
}

// pack 2 floats -> 2 bf16 in a uint (compiler fuses to v_cvt_pk_bf16_f32)
__device__ __forceinline__ unsigned int pk2(float lo, float hi) {
    union { unsigned short s[2]; unsigned int u; } r;
    r.s[0] = f2bf_rn(lo); r.s[1] = f2bf_rn(hi);
    return r.u;
}

__device__ __forceinline__ void gload_lds16(const void* g, void* l) {
    __builtin_amdgcn_global_load_lds(
        (const __attribute__((address_space(1))) void*)g,
        (__attribute__((address_space(3))) void*)l, 16, 0, 0);
}

// ---------------------------------------------------------------------------
// prep_h: transpose each 128x128 fp32 block of the 8 H tensors to bf16.
//   ht[j][blk][k][r] = h_j[blk][r][k]   (j = input order hr1,hi1,...,hi4)
// 256 WGs = jblk(64) x k-quarter(4).
// ---------------------------------------------------------------------------
__global__ __launch_bounds__(256) void prep_h(
    const float* __restrict__ h0, const float* __restrict__ h1,
    const float* __restrict__ h2, const float* __restrict__ h3,
    const float* __restrict__ h4, const float* __restrict__ h5,
    const float* __restrict__ h6, const float* __restrict__ h7,
    unsigned short* __restrict__ ht)
{
    const float* hmap[8] = {h0, h1, h2, h3, h4, h5, h6, h7};
    const int wg = blockIdx.x;            // 256 = jblk(64) x quarter(4)
    const int jblk = wg >> 2, qt = wg & 3;
    const float* src = hmap[jblk >> 3] + (jblk & 7) * 16384;
    unsigned short* dst = ht + jblk * 16384;
    __shared__ unsigned short tile[32 * 129];
    const int t = threadIdx.x;
    #pragma unroll
    for (int i = 0; i < 16; ++i) {
        int idx = t + 256 * i;            // 4096 = r(128) x kk(32)
        int r = idx >> 5, kk = idx & 31;
        tile[kk * 129 + r] = f2bf_rn(src[r * 128 + qt * 32 + kk]);
    }
    __syncthreads();
    #pragma unroll
    for (int i = 0; i < 16; ++i) {
        int idx = t + 256 * i;            // 4096 = k(32) x r(128)
        int k = idx >> 7, r = idx & 127;
        dst[(qt * 32 + k) * 128 + r] = tile[k * 129 + r];
    }
}

// ---------------------------------------------------------------------------
// bilin_main: 256 WGs = (b,p,q), q = bid&7 (XCD-locked). 256 threads =
// 4 waves, wave wn owns output cols wn*32..+32, FULL K=128 (no split-K).
// 32x32x16 MFMA.  Per-wave register budget at 1 wave/SIMD = 512 unified:
//   y accums 128 | xf (X fragments, whole 128-row tile) 128 | u 64.
// Prologue stages BOTH X planes (fp32 read once, perm in address, convert
// in flight) into LDS; each wave then loads xf once per g (g1 reload at
// cc=4, hazard-free: planes written once).  W double-buffered, Lt single:
// LDS = 32+32+64+32 = 160 KB exact.  R9-proven schedule:
//   TOP: issue W(c+1) -> stage A (wfr LDS, xf REGS) -> MID barrier (drains
//   Lt(c)) -> stage B (in-reg 2-shfl transpose + lfr LDS) -> END barrier
//   (drains W(c+1)) -> issue Lt(c+1).
// Epilogue: direct coalesced float2 stores (no reduction, no barrier).
// LDS swizzle: 16B chunk ch of row at LDS[row][ch] = G[row][ch ^ (row&15)].
// ---------------------------------------------------------------------------
__global__ __launch_bounds__(256, 1) void bilin_main(
    const float* __restrict__ x, const int* __restrict__ perm,
    const unsigned short* __restrict__ ht, float* __restrict__ out)
{
    const int wg = blockIdx.x;
    const int q = wg & 7, p = (wg >> 3) & 7, b = wg >> 6;
    const int tid = threadIdx.x;
    const int lane = tid & 63, wn = tid >> 6;      // 4 waves
    const int l31 = lane & 31, hl = lane >> 5;

    __shared__ __align__(16) unsigned short smem[81920];   // 160 KB
    unsigned short* xre_lds = smem;                        // 32 KB
    unsigned short* xim_lds = smem + 16384;                // 32 KB
    // W[par] = smem + 32768 + par*16384 (64 KB)
    unsigned short* llds = smem + 65536;                   // 32 KB

    constexpr int cseq[8]  = {0, 1, 6, 7, 2, 3, 4, 5};
    constexpr int rperm[8] = {0, 1, 3, 2, 4, 5, 7, 6};

    // ---- staging helpers (gload_lds: wave-uniform LDS base + lane*16) ----
    const int wubase = tid & ~63;
    auto stage_h = [&](unsigned short* dst, int blk) {
        const unsigned short* src = ht + blk * 16384;
        #pragma unroll
        for (int r = 0; r < 8; ++r) {
            const int idx = r * 256 + tid;          // 16B chunk 0..2047
            const int row = idx >> 4, cin = idx & 15;
            gload_lds16(src + row * 128 + ((cin ^ (row & 15)) << 3),
                        dst + ((r * 256 + wubase) << 3));
        }
    };

    // swizzled LDS fragment read: row in [0,128), chunk in [0,16)
    auto ldr = [&](const unsigned short* base, int row, int ch) -> bf16x8 {
        return *(const bf16x8*)(base + row * 128 + ((ch ^ (row & 15)) << 3));
    };

    // fused prep_x: fp32 read ONCE -> convert -> both swizzled LDS planes
    auto stage_x_both = [&]() {
        #pragma unroll
        for (int i = 0; i < 8; ++i) {
            const int idx = i * 256 + tid;
            const int row = idx >> 4, cin = idx & 15;
            const int n1 = perm[2 * p + (row >> 6)];
            const int n2 = perm[2 * q + (cin >> 3)];
            const int r1 = row & 63, r2 = (cin & 7) * 8;
            const float* sp = x + ((size_t)((b * 16 + n1) * 64 + r1) * 1024
                                   + n2 * 64 + r2) * 2;
            float4 v0 = *(const float4*)(sp);
            float4 v1 = *(const float4*)(sp + 4);
            float4 v2 = *(const float4*)(sp + 8);
            float4 v3 = *(const float4*)(sp + 12);
            bf16x8 re, im;
            re[0] = (short)f2bf_rn(v0.x); re[1] = (short)f2bf_rn(v0.z);
            re[2] = (short)f2bf_rn(v1.x); re[3] = (short)f2bf_rn(v1.z);
            re[4] = (short)f2bf_rn(v2.x); re[5] = (short)f2bf_rn(v2.z);
            re[6] = (short)f2bf_rn(v3.x); re[7] = (short)f2bf_rn(v3.z);
            im[0] = (short)f2bf_rn(v0.y); im[1] = (short)f2bf_rn(v0.w);
            im[2] = (short)f2bf_rn(v1.y); im[3] = (short)f2bf_rn(v1.w);
            im[4] = (short)f2bf_rn(v2.y); im[5] = (short)f2bf_rn(v2.w);
            im[6] = (short)f2bf_rn(v3.y); im[7] = (short)f2bf_rn(v3.w);
            const int woff = row * 128 + ((cin ^ (row & 15)) << 3);
            *(bf16x8*)(xre_lds + woff) = re;
            *(bf16x8*)(xim_lds + woff) = im;
        }
    };

    // X fragments for the whole 128-row tile, in registers (128 VGPRs)
    bf16x8 xf[4][8];
    auto load_xf = [&](const unsigned short* plane) {
        #pragma unroll
        for (int m2 = 0; m2 < 4; ++m2)
            #pragma unroll
            for (int ks = 0; ks < 8; ++ks)
                xf[m2][ks] = ldr(plane, m2 * 32 + l31, 2 * ks + hl);
    };

    // ---- prologue ----
    stage_h(smem + 32768, rperm[0] * 8 + q);   // W(0)
    stage_h(llds, 0 * 8 + p);                  // Lt(0)
    stage_x_both();
    __syncthreads();          // drains gloads, orders X plane writes
    load_xf(xre_lds);

    f32x16 yre[4], yim[4];
    #pragma unroll
    for (int i = 0; i < 4; ++i) {
        #pragma unroll
        for (int e = 0; e < 16; ++e) { yre[i][e] = 0.f; yim[i][e] = 0.f; }
    }

    #pragma unroll
    for (int cc = 0; cc < 8; ++cc) {
        const unsigned short* wb = smem + 32768 + (cc & 1) * 16384;

        // issue next W (opposite parity, last read in stage A(cc-1)): drains
        // at this c's END barrier
        if (cc < 7)
            stage_h(smem + 32768 + ((cc + 1) & 1) * 16384,
                    rperm[cseq[cc + 1]] * 8 + q);

        // g switch: planes are static after prologue — plain reload
        if (cc == 4) load_xf(xim_lds);

        // ---- stage A: u[m2] = X[m2-rows] . W_c[:, wn-cols], K=128
        f32x16 u[4];
        #pragma unroll
        for (int m2 = 0; m2 < 4; ++m2)
            #pragma unroll
            for (int e = 0; e < 16; ++e) u[m2][e] = 0.f;
        #pragma unroll
        for (int ks = 0; ks < 8; ++ks) {
            bf16x8 wfr = ldr(wb, wn * 32 + l31, 2 * ks + hl);
            #pragma unroll
            for (int m2 = 0; m2 < 4; ++m2)
                u[m2] = MFMA32(xf[m2][ks], wfr, u[m2]);
        }

        __syncthreads();   // MID: drains Lt(c) (issued at END of cc-1)

        // ---- stage B: Y += Lt_c . U, K = 128 (8 k-steps)
        #pragma unroll
        for (int t = 0; t < 8; ++t) {
            // B-frag for k-step t from C-frag u[t>>1]: 2-shfl in-reg
            // transpose (R6-verified exchange, extended f range)
            const int f = t >> 1, qa = (t & 1) * 2, qb = qa + 1;
            unsigned int lo0 = pk2(u[f][4 * qa + 0], u[f][4 * qa + 1]);
            unsigned int lo1 = pk2(u[f][4 * qa + 2], u[f][4 * qa + 3]);
            unsigned int hi0 = pk2(u[f][4 * qb + 0], u[f][4 * qb + 1]);
            unsigned int hi1 = pk2(u[f][4 * qb + 2], u[f][4 * qb + 3]);
            unsigned int send0 = hl ? lo0 : hi0;
            unsigned int send1 = hl ? lo1 : hi1;
            unsigned int sx0 = (unsigned int)__shfl_xor((int)send0, 32);
            unsigned int sx1 = (unsigned int)__shfl_xor((int)send1, 32);
            union { unsigned int d[4]; bf16x8 v; } ufu;
            ufu.d[0] = hl ? sx0 : lo0;
            ufu.d[1] = hl ? sx1 : lo1;
            ufu.d[2] = hl ? hi0 : sx0;
            ufu.d[3] = hl ? hi1 : sx1;
            #pragma unroll
            for (int mt = 0; mt < 4; ++mt) {
                bf16x8 lfr = ldr(llds, mt * 32 + l31, 2 * t + hl);
                if ((cc & 3) < 2) yre[mt] = MFMA32(lfr, ufu.v, yre[mt]);
                else              yim[mt] = MFMA32(lfr, ufu.v, yim[mt]);
            }
        }

        __syncthreads();   // END: all waves done with llds; drains W(c+1)
        if (cc < 7)
            stage_h(llds, cseq[cc + 1] * 8 + p);   // drains at MID(cc+1)
    }

    // ---- epilogue: direct interleaved (re,im) stores, no reduction ----
    float2* o2 = (float2*)out;
    #pragma unroll
    for (int mt = 0; mt < 4; ++mt)
        #pragma unroll
        for (int j = 0; j < 16; ++j) {
            const int row = mt * 32 + (j & 3) + 8 * (j >> 2) + 4 * hl;
            float2 v;
            v.x = yre[mt][j];
            v.y = yim[mt][j];
            o2[(size_t)(b * 1024 + p * 128 + row) * 1024
               + q * 128 + wn * 32 + l31] = v;
        }
}

extern "C" void kernel_launch(void* const* d_in, const int* in_sizes, int n_in,
                              void* d_out, int out_size, void* d_ws, size_t ws_size,
                              hipStream_t stream) {
    const float* x  = (const float*)d_in[0];
    const int* perm = (const int*)d_in[1];
    unsigned short* htp = (unsigned short*)d_ws;   // 2 MB

    hipLaunchKernelGGL(prep_h, dim3(256), dim3(256), 0, stream,
        (const float*)d_in[2], (const float*)d_in[3], (const float*)d_in[4],
        (const float*)d_in[5], (const float*)d_in[6], (const float*)d_in[7],
        (const float*)d_in[8], (const float*)d_in[9], htp);
    hipLaunchKernelGGL(bilin_main, dim3(256), dim3(256), 0, stream,
        x, perm, htp, (float*)d_out);
}